// Round 6
// baseline (236.516 us; speedup 1.0000x reference)
//
#include <hip/hip_runtime.h>
#include <stdint.h>

// Problem constants (fixed shapes from reference)
#define M_DIM 4096   // 2 * 2048 rows of x
#define K_DIM 4096   // in_features
#define N_DIM 4096   // out_features

typedef float f32x4 __attribute__((ext_vector_type(4)));
typedef int   i32x4 __attribute__((ext_vector_type(4)));

// ---------------------------------------------------------------------------
// Fused quant kernel (unchanged from R3/R4/R5).
// ---------------------------------------------------------------------------
__global__ __launch_bounds__(256) void quant_xw(const float* __restrict__ x,
                                                const int* __restrict__ packed,
                                                const float* __restrict__ d,
                                                const float* __restrict__ dmin,
                                                const int* __restrict__ scales,
                                                const int* __restrict__ mins,
                                                int8_t* __restrict__ xq,
                                                float* __restrict__ sx,
                                                int8_t* __restrict__ wq,
                                                float* __restrict__ sw) {
    __shared__ float sa[128], sb[128], red[4];
    if (blockIdx.x < 4096) {
        const int row  = blockIdx.x;
        const int base = threadIdx.x * 16;
        const float* xr = x + (size_t)row * K_DIM + base;
        float4 v[4];
#pragma unroll
        for (int c = 0; c < 4; ++c) v[c] = ((const float4*)xr)[c];
        float am = 0.f;
#pragma unroll
        for (int c = 0; c < 4; ++c) {
            am = fmaxf(am, fabsf(v[c].x)); am = fmaxf(am, fabsf(v[c].y));
            am = fmaxf(am, fabsf(v[c].z)); am = fmaxf(am, fabsf(v[c].w));
        }
#pragma unroll
        for (int off = 32; off; off >>= 1) am = fmaxf(am, __shfl_xor(am, off, 64));
        if ((threadIdx.x & 63) == 0) red[threadIdx.x >> 6] = am;
        __syncthreads();
        float amax = fmaxf(fmaxf(red[0], red[1]), fmaxf(red[2], red[3]));
        amax = fmaxf(amax, 1e-20f);
        const float inv = 127.0f / amax;
        int ow[4];
#pragma unroll
        for (int c = 0; c < 4; ++c) {
            int q0 = __float2int_rn(v[c].x * inv);
            int q1 = __float2int_rn(v[c].y * inv);
            int q2 = __float2int_rn(v[c].z * inv);
            int q3 = __float2int_rn(v[c].w * inv);
            ow[c] = (q0 & 255) | ((q1 & 255) << 8) | ((q2 & 255) << 16) | ((q3 & 255) << 24);
        }
        ((int4*)(xq + (size_t)row * K_DIM + base))[0] = make_int4(ow[0], ow[1], ow[2], ow[3]);
        if (threadIdx.x == 0) sx[row] = amax / 127.0f;
    } else {
        const int n = blockIdx.x - 4096;
        const int t = threadIdx.x;
        float m = 0.f;
        if (t < 128) {
            int sub  = n * 128 + t;
            int sidx = n * 16 + (t >> 3);
            float dd = d[sidx], dm = dmin[sidx];
            float a = dd * (float)scales[sub] * (1.0f / 945.0f);
            float b = dd * (float)mins[sub] * (1.0f / 63.0f) + dm;
            sa[t] = a; sb[t] = b;
            m = 15.0f * a + b;
        }
#pragma unroll
        for (int off = 32; off; off >>= 1) m = fmaxf(m, __shfl_xor(m, off, 64));
        if ((t & 63) == 0) red[t >> 6] = m;
        __syncthreads();
        float rowmax = fmaxf(fmaxf(red[0], red[1]), fmaxf(red[2], red[3]));
        rowmax = fmaxf(rowmax, 1e-20f);
        const float inv = 127.0f / rowmax;

        const int sub = t >> 1;
        const float a = sa[sub] * inv;
        const float b = sb[sub] * inv;
        const int4* p4 = (const int4*)(packed + (size_t)n * (K_DIM / 2) + t * 8);
        int4 pv0 = p4[0], pv1 = p4[1];
        int bytes[8] = {pv0.x, pv0.y, pv0.z, pv0.w, pv1.x, pv1.y, pv1.z, pv1.w};
        int ow[4];
#pragma unroll
        for (int c = 0; c < 4; ++c) {
            int b0 = bytes[2 * c], b1 = bytes[2 * c + 1];
            int q0 = __float2int_rn((float)(b0 & 15) * a + b);
            int q1 = __float2int_rn((float)((b0 >> 4) & 15) * a + b);
            int q2 = __float2int_rn((float)(b1 & 15) * a + b);
            int q3 = __float2int_rn((float)((b1 >> 4) & 15) * a + b);
            ow[c] = (q0 & 255) | ((q1 & 255) << 8) | ((q2 & 255) << 16) | ((q3 & 255) << 24);
        }
        ((int4*)(wq + (size_t)n * K_DIM + t * 16))[0] = make_int4(ow[0], ow[1], ow[2], ow[3]);
        if (t == 0) sw[n] = rowmax / 127.0f;
    }
}

// ---------------------------------------------------------------------------
// GEMM R6: C[M,N](fp32) = sx[m]*sw[n] * (Aq . Bq^T), i8 MFMA 16x16x64.
//
// THE change (R2/R4/R5 invariant): 256^2 tile => 128 KiB LDS => 1 block/CU =>
// every vmcnt+barrier stalls the WHOLE CU (no independent barrier domain to
// cover the structural stage/sync overhead; m114/m233 mechanism). Now:
//   tile 128x256, BK=64 B, 256 thr / 4 waves (2Mx2N, wave tile 64x128 keeps
//   LDS-read/MFMA at the 375 B/MFMA minimum), dbuf LDS = 48 KiB
//   => 2 blocks/CU, each SIMD hosts 1 wave from EACH block: when block A
//   sits at WAITV/BARRIER, block B's wave keeps the MFMA pipe fed.
// Schedule: simple m97-style {STAGE(next); COMPUTE(cur); WAITV(0); BARRIER}
// per 64-B K-tile (64 iters) — cross-block async replaces intra-block
// hand-pipelining (which R2/R4/R5 proved has no headroom at 1 block/CU).
//
// LDS layout (rows of 64 B = 4 chunks of 16 B): chunk c of row r at slot
// c ^ (r&3) (involution; staging pre-swizzles the global source, read
// applies the same XOR -> rule #21). Quad census over a wave's ds_read_b128:
// all 8 bank-quads x 8 lanes -> schedulable conflict-free (0 expected).
// ---------------------------------------------------------------------------
#define BK 64   // bytes of K per K-tile (1 MFMA k-step of 64)

__device__ __forceinline__ void async_copy16(void* lds, const void* g) {
    __builtin_amdgcn_global_load_lds(
        (const __attribute__((address_space(1))) void*)g,
        (__attribute__((address_space(3))) void*)lds, 16, 0, 0);
}

#define BARRIER() asm volatile("s_barrier" ::: "memory")
#define WAITV(n)  asm volatile("s_waitcnt vmcnt(" #n ")" ::: "memory")
#define mfma64(a, b, c) __builtin_amdgcn_mfma_i32_16x16x64_i8(a, b, c, 0, 0, 0)

__global__ __launch_bounds__(256) void gemm_i8(const int8_t* __restrict__ A,
                                               const int8_t* __restrict__ B,
                                               const float* __restrict__ sx,
                                               const float* __restrict__ sw,
                                               float* __restrict__ C) {
    // dbuf: A 128x64 B (8 KB) x2 + B 256x64 B (16 KB) x2 = 48 KiB
    __shared__ int8_t sA[2][128 * 64];
    __shared__ int8_t sB[2][256 * 64];

    const int tid  = threadIdx.x;
    const int wave = tid >> 6;
    const int lane = tid & 63;
    const int wm = wave >> 1;       // 0..1 (M split)
    const int wn = wave & 1;        // 0..1 (N split)
    const int r4 = lane & 15;
    const int q  = lane >> 4;       // k-chunk index 0..3

    // XCD-aware bijective swizzle: 512 blocks = 8 XCDs x 64 contiguous tiles
    const int bid = blockIdx.x;
    const int lid = (bid & 7) * 64 + (bid >> 3);
    const int m0 = (lid & 31) * 128;      // 32 M-tiles
    const int n0 = (lid >> 5) * 256;      // 16 N-tiles

    i32x4 acc[4][8] = {};           // [m][n] -> 128 acc regs
    i32x4 aF[4], bF[8];

    // ---- staging map: instr l: chunk p = l*256 + tid; row = p>>2 (64/instr),
    // slot = p&3, logical chunk c = slot ^ (row&3). (row&3 invariant in l.)
    const int rowS = tid >> 2;                      // 0..63
    const int cS   = (tid & 3) ^ (rowS & 3);
    const size_t rs64 = (size_t)64 * K_DIM;
    const int8_t* gA = A + (size_t)(m0 + rowS) * K_DIM + cS * 16;
    const int8_t* gB = B + (size_t)(n0 + rowS) * K_DIM + cS * 16;
    const int ldsW = wave * 1024;   // wave-uniform dest base (bytes)

#define STAGE(buf, koff)                                                  \
    do {                                                                  \
        async_copy16(&sA[buf][ldsW],         gA + (koff));                \
        async_copy16(&sA[buf][4096 + ldsW],  gA + rs64 + (koff));         \
        async_copy16(&sB[buf][ldsW],         gB + (koff));                \
        async_copy16(&sB[buf][4096 + ldsW],  gB + rs64 + (koff));         \
        async_copy16(&sB[buf][8192 + ldsW],  gB + 2 * rs64 + (koff));     \
        async_copy16(&sB[buf][12288 + ldsW], gB + 3 * rs64 + (koff));     \
    } while (0)

    // ---- fragment LDS offsets: A row = wm*64+m*16+r4; B row = wn*128+n*16+r4
    // slot = q ^ (row&3); row&3 == r4&3 for all frags.
    int aOff[4], bOff[8];
    {
        const int sl = (q ^ (r4 & 3)) * 16;
#pragma unroll
        for (int m = 0; m < 4; ++m)
            aOff[m] = (wm * 64 + m * 16 + r4) * 64 + sl;
#pragma unroll
        for (int n = 0; n < 8; ++n)
            bOff[n] = (wn * 128 + n * 16 + r4) * 64 + sl;
    }

#define COMPUTE(buf)                                                      \
    do {                                                                  \
        _Pragma("unroll") for (int m = 0; m < 4; ++m)                     \
            aF[m] = *(const i32x4*)&sA[buf][aOff[m]];                     \
        _Pragma("unroll") for (int n = 0; n < 8; ++n)                     \
            bF[n] = *(const i32x4*)&sB[buf][bOff[n]];                     \
        __builtin_amdgcn_s_setprio(1);                                    \
        _Pragma("unroll") for (int n = 0; n < 8; ++n)                     \
        _Pragma("unroll") for (int m = 0; m < 4; ++m)                     \
            acc[m][n] = mfma64(aF[m], bF[n], acc[m][n]);                  \
        __builtin_amdgcn_s_setprio(0);                                    \
    } while (0)

    // ---- prologue: tile 0 -> buf 0 ----
    STAGE(0, 0);
    WAITV(0);
    BARRIER();

#pragma unroll 1
    for (int t = 0; t < 63; ++t) {
        const int p = t & 1;
        STAGE(p ^ 1, (t + 1) * BK);   // into buffer read last iter (barrier'd)
        COMPUTE(p);                   // 12 ds_read_b128 + 32 MFMA
        WAITV(0);                     // this iter's 6 loads arrived
        BARRIER();                    // all 24 (4 waves) visible; WAR gate
    }
    COMPUTE(1);                       // tile 63

    // ---- C write: C/D layout col = lane&15, row = (lane>>4)*4 + reg ----
#pragma unroll
    for (int m = 0; m < 4; ++m) {
        const int rbase = m0 + wm * 64 + m * 16 + q * 4;
        const float4 s4 = *(const float4*)&sx[rbase];
#pragma unroll
        for (int n = 0; n < 8; ++n) {
            const int col = n0 + wn * 128 + n * 16 + r4;
            const float swc = sw[col];
            float* cp = C + (size_t)rbase * N_DIM + col;
            cp[0 * N_DIM] = (float)acc[m][n][0] * s4.x * swc;
            cp[1 * N_DIM] = (float)acc[m][n][1] * s4.y * swc;
            cp[2 * N_DIM] = (float)acc[m][n][2] * s4.z * swc;
            cp[3 * N_DIM] = (float)acc[m][n][3] * s4.w * swc;
        }
    }
#undef STAGE
#undef COMPUTE
}

// ---------------------------------------------------------------------------
// Launch: ws usage = 16.7 MB xq + 16.7 MB wq + 32 KB scales.
// ---------------------------------------------------------------------------
extern "C" void kernel_launch(void* const* d_in, const int* in_sizes, int n_in,
                              void* d_out, int out_size, void* d_ws, size_t ws_size,
                              hipStream_t stream) {
    const float* x      = (const float*)d_in[0];
    const int*   packed = (const int*)d_in[1];
    const float* d      = (const float*)d_in[2];
    const float* dmin   = (const float*)d_in[3];
    const int*   scales = (const int*)d_in[4];
    const int*   mins   = (const int*)d_in[5];
    float* out = (float*)d_out;

    int8_t* xq = (int8_t*)d_ws;                               // 16.7 MB
    int8_t* wq = xq + (size_t)M_DIM * K_DIM;                  // 16.7 MB
    float*  sx = (float*)(wq + (size_t)N_DIM * K_DIM);        // 16 KB
    float*  sw = sx + M_DIM;                                  // 16 KB

    quant_xw<<<8192, 256, 0, stream>>>(x, packed, d, dmin, scales, mins,
                                       xq, sx, wq, sw);
    gemm_i8<<<512, 256, 0, stream>>>(xq, wq, sx, sw, out);
}

// Round 7
// 235.576 us; speedup vs baseline: 1.0040x; 1.0040x over previous
//
#include <hip/hip_runtime.h>
#include <stdint.h>

// Problem constants (fixed shapes from reference)
#define M_DIM 4096   // 2 * 2048 rows of x
#define K_DIM 4096   // in_features
#define N_DIM 4096   // out_features

typedef float f32x4 __attribute__((ext_vector_type(4)));
typedef int   i32x4 __attribute__((ext_vector_type(4)));

// ---------------------------------------------------------------------------
// Fused quant kernel (unchanged from R3..R6).
// ---------------------------------------------------------------------------
__global__ __launch_bounds__(256) void quant_xw(const float* __restrict__ x,
                                                const int* __restrict__ packed,
                                                const float* __restrict__ d,
                                                const float* __restrict__ dmin,
                                                const int* __restrict__ scales,
                                                const int* __restrict__ mins,
                                                int8_t* __restrict__ xq,
                                                float* __restrict__ sx,
                                                int8_t* __restrict__ wq,
                                                float* __restrict__ sw) {
    __shared__ float sa[128], sb[128], red[4];
    if (blockIdx.x < 4096) {
        const int row  = blockIdx.x;
        const int base = threadIdx.x * 16;
        const float* xr = x + (size_t)row * K_DIM + base;
        float4 v[4];
#pragma unroll
        for (int c = 0; c < 4; ++c) v[c] = ((const float4*)xr)[c];
        float am = 0.f;
#pragma unroll
        for (int c = 0; c < 4; ++c) {
            am = fmaxf(am, fabsf(v[c].x)); am = fmaxf(am, fabsf(v[c].y));
            am = fmaxf(am, fabsf(v[c].z)); am = fmaxf(am, fabsf(v[c].w));
        }
#pragma unroll
        for (int off = 32; off; off >>= 1) am = fmaxf(am, __shfl_xor(am, off, 64));
        if ((threadIdx.x & 63) == 0) red[threadIdx.x >> 6] = am;
        __syncthreads();
        float amax = fmaxf(fmaxf(red[0], red[1]), fmaxf(red[2], red[3]));
        amax = fmaxf(amax, 1e-20f);
        const float inv = 127.0f / amax;
        int ow[4];
#pragma unroll
        for (int c = 0; c < 4; ++c) {
            int q0 = __float2int_rn(v[c].x * inv);
            int q1 = __float2int_rn(v[c].y * inv);
            int q2 = __float2int_rn(v[c].z * inv);
            int q3 = __float2int_rn(v[c].w * inv);
            ow[c] = (q0 & 255) | ((q1 & 255) << 8) | ((q2 & 255) << 16) | ((q3 & 255) << 24);
        }
        ((int4*)(xq + (size_t)row * K_DIM + base))[0] = make_int4(ow[0], ow[1], ow[2], ow[3]);
        if (threadIdx.x == 0) sx[row] = amax / 127.0f;
    } else {
        const int n = blockIdx.x - 4096;
        const int t = threadIdx.x;
        float m = 0.f;
        if (t < 128) {
            int sub  = n * 128 + t;
            int sidx = n * 16 + (t >> 3);
            float dd = d[sidx], dm = dmin[sidx];
            float a = dd * (float)scales[sub] * (1.0f / 945.0f);
            float b = dd * (float)mins[sub] * (1.0f / 63.0f) + dm;
            sa[t] = a; sb[t] = b;
            m = 15.0f * a + b;
        }
#pragma unroll
        for (int off = 32; off; off >>= 1) m = fmaxf(m, __shfl_xor(m, off, 64));
        if ((t & 63) == 0) red[t >> 6] = m;
        __syncthreads();
        float rowmax = fmaxf(fmaxf(red[0], red[1]), fmaxf(red[2], red[3]));
        rowmax = fmaxf(rowmax, 1e-20f);
        const float inv = 127.0f / rowmax;

        const int sub = t >> 1;
        const float a = sa[sub] * inv;
        const float b = sb[sub] * inv;
        const int4* p4 = (const int4*)(packed + (size_t)n * (K_DIM / 2) + t * 8);
        int4 pv0 = p4[0], pv1 = p4[1];
        int bytes[8] = {pv0.x, pv0.y, pv0.z, pv0.w, pv1.x, pv1.y, pv1.z, pv1.w};
        int ow[4];
#pragma unroll
        for (int c = 0; c < 4; ++c) {
            int b0 = bytes[2 * c], b1 = bytes[2 * c + 1];
            int q0 = __float2int_rn((float)(b0 & 15) * a + b);
            int q1 = __float2int_rn((float)((b0 >> 4) & 15) * a + b);
            int q2 = __float2int_rn((float)(b1 & 15) * a + b);
            int q3 = __float2int_rn((float)((b1 >> 4) & 15) * a + b);
            ow[c] = (q0 & 255) | ((q1 & 255) << 8) | ((q2 & 255) << 16) | ((q3 & 255) << 24);
        }
        ((int4*)(wq + (size_t)n * K_DIM + t * 16))[0] = make_int4(ow[0], ow[1], ow[2], ow[3]);
        if (t == 0) sw[n] = rowmax / 127.0f;
    }
}

// ---------------------------------------------------------------------------
// GEMM R7 = R6 with ONE fix: the 64-B-row LDS swizzle.
//
// R6 measured EXACTLY 4 conflict units per ds_read_b128 (6,291,456 total =
// 512 blk x 4 waves x 64 iters x 12 reads x 4): with slot = q ^ (row&3),
// quad(lane) = (4*(r4&1) + q^(r4&3))&7 and each consecutive-8-lane group
// hits only 4 distinct quads twice -> 2-way serialization on every fragment
// read. Fix: f(row) = (row>>1)&3. Then quad = 4*(r4&1) + (q ^ ((r4>>1)&3));
// enumeration: q=0, r4=0..7 -> {0,4,1,5,2,6,3,7} (all 8), and every other
// 8-lane group likewise (XOR by const q permutes within halves). Store side
// pre-swizzles the global source with the same involution (rule #21):
// cS = (tid&3) ^ ((rowS>>1)&3); f is invariant across the +64-row second
// load instr (64>>1 = 32 == 0 mod 4).
//
// Structure (unchanged from R6): tile 128x256, BK=64, 256 thr / 4 waves
// (2Mx2N), dbuf LDS 48 KiB => 2 blocks/CU (independent barrier domains cover
// each other's stage/sync stalls — R6's VALUBusy 15->45% shows the overlap
// engaging; it was spent on conflicts).
// ---------------------------------------------------------------------------
#define BK 64   // bytes of K per K-tile (1 MFMA k-step of 64)

__device__ __forceinline__ void async_copy16(void* lds, const void* g) {
    __builtin_amdgcn_global_load_lds(
        (const __attribute__((address_space(1))) void*)g,
        (__attribute__((address_space(3))) void*)lds, 16, 0, 0);
}

#define BARRIER() asm volatile("s_barrier" ::: "memory")
#define WAITV(n)  asm volatile("s_waitcnt vmcnt(" #n ")" ::: "memory")
#define mfma64(a, b, c) __builtin_amdgcn_mfma_i32_16x16x64_i8(a, b, c, 0, 0, 0)

__global__ __launch_bounds__(256) void gemm_i8(const int8_t* __restrict__ A,
                                               const int8_t* __restrict__ B,
                                               const float* __restrict__ sx,
                                               const float* __restrict__ sw,
                                               float* __restrict__ C) {
    // dbuf: A 128x64 B (8 KB) x2 + B 256x64 B (16 KB) x2 = 48 KiB
    __shared__ int8_t sA[2][128 * 64];
    __shared__ int8_t sB[2][256 * 64];

    const int tid  = threadIdx.x;
    const int wave = tid >> 6;
    const int lane = tid & 63;
    const int wm = wave >> 1;       // 0..1 (M split)
    const int wn = wave & 1;        // 0..1 (N split)
    const int r4 = lane & 15;
    const int q  = lane >> 4;       // k-chunk index 0..3

    // XCD-aware bijective swizzle: 512 blocks = 8 XCDs x 64 contiguous tiles
    const int bid = blockIdx.x;
    const int lid = (bid & 7) * 64 + (bid >> 3);
    const int m0 = (lid & 31) * 128;      // 32 M-tiles
    const int n0 = (lid >> 5) * 256;      // 16 N-tiles

    i32x4 acc[4][8] = {};           // [m][n] -> 128 acc regs
    i32x4 aF[4], bF[8];

    // ---- staging map: instr l: chunk p = l*256 + tid; row = p>>2,
    // slot = p&3, logical chunk c = slot ^ ((row>>1)&3). ((row>>1)&3
    // invariant in l: l*64>>1 = l*32 == 0 mod 4.)
    const int rowS = tid >> 2;                      // 0..63
    const int cS   = (tid & 3) ^ ((rowS >> 1) & 3);
    const size_t rs64 = (size_t)64 * K_DIM;
    const int8_t* gA = A + (size_t)(m0 + rowS) * K_DIM + cS * 16;
    const int8_t* gB = B + (size_t)(n0 + rowS) * K_DIM + cS * 16;
    const int ldsW = wave * 1024;   // wave-uniform dest base (bytes)

#define STAGE(buf, koff)                                                  \
    do {                                                                  \
        async_copy16(&sA[buf][ldsW],         gA + (koff));                \
        async_copy16(&sA[buf][4096 + ldsW],  gA + rs64 + (koff));         \
        async_copy16(&sB[buf][ldsW],         gB + (koff));                \
        async_copy16(&sB[buf][4096 + ldsW],  gB + rs64 + (koff));         \
        async_copy16(&sB[buf][8192 + ldsW],  gB + 2 * rs64 + (koff));     \
        async_copy16(&sB[buf][12288 + ldsW], gB + 3 * rs64 + (koff));     \
    } while (0)

    // ---- fragment LDS offsets: A row = wm*64+m*16+r4; B row = wn*128+n*16+r4
    // slot = q ^ ((row>>1)&3); bases are multiples of 16 so (row>>1)&3 ==
    // (r4>>1)&3 for all frags.
    int aOff[4], bOff[8];
    {
        const int sl = (q ^ ((r4 >> 1) & 3)) * 16;
#pragma unroll
        for (int m = 0; m < 4; ++m)
            aOff[m] = (wm * 64 + m * 16 + r4) * 64 + sl;
#pragma unroll
        for (int n = 0; n < 8; ++n)
            bOff[n] = (wn * 128 + n * 16 + r4) * 64 + sl;
    }

#define COMPUTE(buf)                                                      \
    do {                                                                  \
        _Pragma("unroll") for (int m = 0; m < 4; ++m)                     \
            aF[m] = *(const i32x4*)&sA[buf][aOff[m]];                     \
        _Pragma("unroll") for (int n = 0; n < 8; ++n)                     \
            bF[n] = *(const i32x4*)&sB[buf][bOff[n]];                     \
        __builtin_amdgcn_s_setprio(1);                                    \
        _Pragma("unroll") for (int n = 0; n < 8; ++n)                     \
        _Pragma("unroll") for (int m = 0; m < 4; ++m)                     \
            acc[m][n] = mfma64(aF[m], bF[n], acc[m][n]);                  \
        __builtin_amdgcn_s_setprio(0);                                    \
    } while (0)

    // ---- prologue: tile 0 -> buf 0 ----
    STAGE(0, 0);
    WAITV(0);
    BARRIER();

#pragma unroll 1
    for (int t = 0; t < 63; ++t) {
        const int p = t & 1;
        STAGE(p ^ 1, (t + 1) * BK);   // into buffer read last iter (barrier'd)
        COMPUTE(p);                   // 12 ds_read_b128 + 32 MFMA
        WAITV(0);                     // this iter's 6 loads arrived
        BARRIER();                    // all 24 (4 waves) visible; WAR gate
    }
    COMPUTE(1);                       // tile 63

    // ---- C write: C/D layout col = lane&15, row = (lane>>4)*4 + reg ----
#pragma unroll
    for (int m = 0; m < 4; ++m) {
        const int rbase = m0 + wm * 64 + m * 16 + q * 4;
        const float4 s4 = *(const float4*)&sx[rbase];
#pragma unroll
        for (int n = 0; n < 8; ++n) {
            const int col = n0 + wn * 128 + n * 16 + r4;
            const float swc = sw[col];
            float* cp = C + (size_t)rbase * N_DIM + col;
            cp[0 * N_DIM] = (float)acc[m][n][0] * s4.x * swc;
            cp[1 * N_DIM] = (float)acc[m][n][1] * s4.y * swc;
            cp[2 * N_DIM] = (float)acc[m][n][2] * s4.z * swc;
            cp[3 * N_DIM] = (float)acc[m][n][3] * s4.w * swc;
        }
    }
#undef STAGE
#undef COMPUTE
}

// ---------------------------------------------------------------------------
// Launch: ws usage = 16.7 MB xq + 16.7 MB wq + 32 KB scales.
// ---------------------------------------------------------------------------
extern "C" void kernel_launch(void* const* d_in, const int* in_sizes, int n_in,
                              void* d_out, int out_size, void* d_ws, size_t ws_size,
                              hipStream_t stream) {
    const float* x      = (const float*)d_in[0];
    const int*   packed = (const int*)d_in[1];
    const float* d      = (const float*)d_in[2];
    const float* dmin   = (const float*)d_in[3];
    const int*   scales = (const int*)d_in[4];
    const int*   mins   = (const int*)d_in[5];
    float* out = (float*)d_out;

    int8_t* xq = (int8_t*)d_ws;                               // 16.7 MB
    int8_t* wq = xq + (size_t)M_DIM * K_DIM;                  // 16.7 MB
    float*  sx = (float*)(wq + (size_t)N_DIM * K_DIM);        // 16 KB
    float*  sw = sx + M_DIM;                                  // 16 KB

    quant_xw<<<8192, 256, 0, stream>>>(x, packed, d, dmin, scales, mins,
                                       xq, sx, wq, sw);
    gemm_i8<<<512, 256, 0, stream>>>(xq, wq, sx, sw, out);
}

// Round 8
// 220.074 us; speedup vs baseline: 1.0747x; 1.0704x over previous
//
#include <hip/hip_runtime.h>
#include <stdint.h>

// Problem constants (fixed shapes from reference)
#define M_DIM 4096   // 2 * 2048 rows of x
#define K_DIM 4096   // in_features
#define N_DIM 4096   // out_features

typedef float f32x4 __attribute__((ext_vector_type(4)));
typedef int   i32x4 __attribute__((ext_vector_type(4)));

// ---------------------------------------------------------------------------
// R8 quant: one WAVE per row, no LDS, no __syncthreads, shfl-only reduce,
// fully-coalesced chunked access (16 B/lane contiguous per instruction).
// Blocks [0,1024): x rows (4/block). Blocks [1024,2048): W rows (4/block).
// Output bytes are identical to the R3-R7 quant kernels (same formulas, same
// memory layout) — only the thread<->data assignment changed.
// ---------------------------------------------------------------------------
__global__ __launch_bounds__(256) void quant_xw(const float* __restrict__ x,
                                                const int* __restrict__ packed,
                                                const float* __restrict__ d,
                                                const float* __restrict__ dmin,
                                                const int* __restrict__ scales,
                                                const int* __restrict__ mins,
                                                int8_t* __restrict__ xq,
                                                float* __restrict__ sx,
                                                int8_t* __restrict__ wq,
                                                float* __restrict__ sw) {
    const int wave = threadIdx.x >> 6;
    const int lane = threadIdx.x & 63;
    if (blockIdx.x < 1024) {
        // ---- x fp32 -> i8, per-row scale. Row = 4096 floats = 1024 float4;
        // chunk c: lane reads float4 at c*64+lane (1 KB/instr, coalesced).
        const int row = blockIdx.x * 4 + wave;
        const float4* xr = (const float4*)(x + (size_t)row * K_DIM);
        float4 v[16];
#pragma unroll
        for (int c = 0; c < 16; ++c) v[c] = xr[c * 64 + lane];
        float am = 0.f;
#pragma unroll
        for (int c = 0; c < 16; ++c) {
            am = fmaxf(am, fabsf(v[c].x)); am = fmaxf(am, fabsf(v[c].y));
            am = fmaxf(am, fabsf(v[c].z)); am = fmaxf(am, fabsf(v[c].w));
        }
#pragma unroll
        for (int off = 32; off; off >>= 1) am = fmaxf(am, __shfl_xor(am, off, 64));
        am = fmaxf(am, 1e-20f);
        const float inv = 127.0f / am;
        int* oq = (int*)(xq + (size_t)row * K_DIM);
#pragma unroll
        for (int c = 0; c < 16; ++c) {
            int q0 = __float2int_rn(v[c].x * inv);
            int q1 = __float2int_rn(v[c].y * inv);
            int q2 = __float2int_rn(v[c].z * inv);
            int q3 = __float2int_rn(v[c].w * inv);
            oq[c * 64 + lane] = (q0 & 255) | ((q1 & 255) << 8) |
                                ((q2 & 255) << 16) | ((q3 & 255) << 24);
        }
        if (lane == 0) sx[row] = am / 127.0f;
    } else {
        // ---- Q4_K dequant -> i8 W, per-row scale. Row = 2048 packed int32
        // (one byte-pair each) = 512 int4; lane owns subblocks lane, lane+64.
        const int n = (blockIdx.x - 1024) * 4 + wave;
        const int sb = n * 128;
        const float s0  = (float)scales[sb + lane];
        const float s1  = (float)scales[sb + 64 + lane];
        const float mn0 = (float)mins[sb + lane];
        const float mn1 = (float)mins[sb + 64 + lane];
        const int di = n * 16;
        const float dd0 = d[di + (lane >> 3)];
        const float dd1 = d[di + 8 + (lane >> 3)];
        const float dm0 = dmin[di + (lane >> 3)];
        const float dm1 = dmin[di + 8 + (lane >> 3)];
        const float a0 = dd0 * s0 * (1.0f / 945.0f);
        const float b0 = dd0 * mn0 * (1.0f / 63.0f) + dm0;
        const float a1 = dd1 * s1 * (1.0f / 945.0f);
        const float b1 = dd1 * mn1 * (1.0f / 63.0f) + dm1;
        float m = fmaxf(15.0f * a0 + b0, 15.0f * a1 + b1);
#pragma unroll
        for (int off = 32; off; off >>= 1) m = fmaxf(m, __shfl_xor(m, off, 64));
        m = fmaxf(m, 1e-20f);
        const float inv = 127.0f / m;
        const float A0 = a0 * inv, B0 = b0 * inv;
        const float A1 = a1 * inv, B1 = b1 * inv;
        // chunk c: int4 at c*64+lane (1 KB/instr); its 4 ints = 8 weights all
        // in subblock (c&3)*16 + (lane>>2) of half c>>2; write int2 (512 B).
        const int4* pr = (const int4*)(packed + (size_t)n * (K_DIM / 2));
        int2* outr = (int2*)(wq + (size_t)n * K_DIM);
#pragma unroll
        for (int c = 0; c < 8; ++c) {
            const int4 pv = pr[c * 64 + lane];
            const int sIdx = (c & 3) * 16 + (lane >> 2);
            const float a = (c < 4) ? __shfl(A0, sIdx, 64) : __shfl(A1, sIdx, 64);
            const float b = (c < 4) ? __shfl(B0, sIdx, 64) : __shfl(B1, sIdx, 64);
            int q0 = __float2int_rn((float)(pv.x & 15) * a + b);
            int q1 = __float2int_rn((float)((pv.x >> 4) & 15) * a + b);
            int q2 = __float2int_rn((float)(pv.y & 15) * a + b);
            int q3 = __float2int_rn((float)((pv.y >> 4) & 15) * a + b);
            int q4 = __float2int_rn((float)(pv.z & 15) * a + b);
            int q5 = __float2int_rn((float)((pv.z >> 4) & 15) * a + b);
            int q6 = __float2int_rn((float)(pv.w & 15) * a + b);
            int q7 = __float2int_rn((float)((pv.w >> 4) & 15) * a + b);
            int2 o;
            o.x = (q0 & 255) | ((q1 & 255) << 8) | ((q2 & 255) << 16) | ((q3 & 255) << 24);
            o.y = (q4 & 255) | ((q5 & 255) << 8) | ((q6 & 255) << 16) | ((q7 & 255) << 24);
            outr[c * 64 + lane] = o;
        }
        if (lane == 0) sw[n] = m / 127.0f;
    }
}

// ---------------------------------------------------------------------------
// GEMM: R5 verbatim (best measured: 74 µs, 0 conflicts, VGPR 120).
// 256x256 tile, 4Mx2N waves, 2 barriers/tile, counted WAITV(2), k-sweep
// MFMA order. R6/R7's 2-blocks/CU variant regressed (98 µs) — reverted.
// ---------------------------------------------------------------------------
#define BK 128   // bytes of K per K-tile (2 MFMA k-steps of 64)

__device__ __forceinline__ void async_copy16(void* lds, const void* g) {
    __builtin_amdgcn_global_load_lds(
        (const __attribute__((address_space(1))) void*)g,
        (__attribute__((address_space(3))) void*)lds, 16, 0, 0);
}

#define BARRIER() asm volatile("s_barrier" ::: "memory")
#define WAITV(n)  asm volatile("s_waitcnt vmcnt(" #n ")" ::: "memory")
#define LGKM0()   asm volatile("s_waitcnt lgkmcnt(0)" ::: "memory")
#define mfma64(a, b, c) __builtin_amdgcn_mfma_i32_16x16x64_i8(a, b, c, 0, 0, 0)

__global__ __launch_bounds__(512, 2) void gemm_i8(const int8_t* __restrict__ A,
                                                  const int8_t* __restrict__ B,
                                                  const float* __restrict__ sx,
                                                  const float* __restrict__ sw,
                                                  float* __restrict__ C) {
    __shared__ int8_t sA[2][2][128 * 128];
    __shared__ int8_t sB[2][2][128 * 128];

    const int tid  = threadIdx.x;
    const int wave = tid >> 6;
    const int lane = tid & 63;
    const int wm = wave >> 1;       // 0..3  (M split)
    const int wn = wave & 1;        // 0..1  (N split = B half)
    const int r4 = lane & 15;
    const int q  = lane >> 4;
    const int ah = wm >> 1;         // wave's A half region

    // XCD-aware bijective swizzle
    const int bid = blockIdx.x;
    const int lid = (bid & 7) * 32 + (bid >> 3);
    const int m0 = (lid & 15) * 256;
    const int n0 = (lid >> 4) * 256;

    i32x4 acc[4][8] = {};           // [m][n] -> 128 acc regs
    i32x4 aF[2][4];                 // [ks][m]  A(t), held all tile
    i32x4 bFa[2][2], bFb[2][2];     // [ks][nn] ping-pong B groups

    // ---- staging map ----
    const int rowS = tid >> 3;
    const int cS   = (tid & 7) ^ (rowS & 7);
    const size_t rs64 = (size_t)64 * K_DIM;
    const int8_t* gAh[2];
    const int8_t* gBh[2];
    gAh[0] = A + (size_t)(m0 + rowS) * K_DIM + cS * 16;
    gAh[1] = gAh[0] + (size_t)128 * K_DIM;
    gBh[0] = B + (size_t)(n0 + rowS) * K_DIM + cS * 16;
    gBh[1] = gBh[0] + (size_t)128 * K_DIM;
    const int ldsW = wave * 1024;

#define STAGE_A(buf, half, koff)                                          \
    do {                                                                  \
        async_copy16(&sA[buf][half][ldsW],        gAh[half] + (koff));    \
        async_copy16(&sA[buf][half][ldsW + 8192], gAh[half] + rs64 + (koff)); \
    } while (0)
#define STAGE_B(buf, half, koff)                                          \
    do {                                                                  \
        async_copy16(&sB[buf][half][ldsW],        gBh[half] + (koff));    \
        async_copy16(&sB[buf][half][ldsW + 8192], gBh[half] + rs64 + (koff)); \
    } while (0)

    // ---- fragment LDS base offsets ----
    int aOffB[2], bOffB[2];
#pragma unroll
    for (int ks = 0; ks < 2; ++ks) {
        const int sl = (((ks * 4 + q) ^ (r4 & 7)) * 16);
        aOffB[ks] = ((wm & 1) * 64 + r4) * 128 + sl;
        bOffB[ks] = r4 * 128 + sl;
    }

#define RD_A(buf, ks, m) (*(const i32x4*)&sA[buf][ah][aOffB[ks] + (m) * 2048])
#define RD_B(buf, ks, n) (*(const i32x4*)&sB[buf][wn][bOffB[ks] + (n) * 2048])

// 16 MFMA for B-group g: k0 sweep (8 indep accs), weave, k1 sweep, weave.
#define MMA_BW(g, BC, BN, rb, ng)                                         \
    do {                                                                  \
        __builtin_amdgcn_s_setprio(1);                                    \
        _Pragma("unroll") for (int m = 0; m < 4; ++m)                     \
        _Pragma("unroll") for (int nn = 0; nn < 2; ++nn)                  \
            acc[m][2*(g)+nn] = mfma64(aF[0][m], BC[0][nn], acc[m][2*(g)+nn]); \
        BN[0][0] = RD_B(rb, 0, 2*(ng));                                  \
        BN[0][1] = RD_B(rb, 0, 2*(ng) + 1);                              \
        _Pragma("unroll") for (int m = 0; m < 4; ++m)                     \
        _Pragma("unroll") for (int nn = 0; nn < 2; ++nn)                  \
            acc[m][2*(g)+nn] = mfma64(aF[1][m], BC[1][nn], acc[m][2*(g)+nn]); \
        BN[1][0] = RD_B(rb, 1, 2*(ng));                                  \
        BN[1][1] = RD_B(rb, 1, 2*(ng) + 1);                              \
        __builtin_amdgcn_s_setprio(0);                                    \
    } while (0)

// grp3: k0 sweep; weave aF[0],grp0-B k0 of next tile; k1 sweep; weave rest.
#define MMA_P4(BC, BN, nb)                                                \
    do {                                                                  \
        __builtin_amdgcn_s_setprio(1);                                    \
        _Pragma("unroll") for (int m = 0; m < 4; ++m)                     \
        _Pragma("unroll") for (int nn = 0; nn < 2; ++nn)                  \
            acc[m][6+nn] = mfma64(aF[0][m], BC[0][nn], acc[m][6+nn]);     \
        _Pragma("unroll") for (int m = 0; m < 4; ++m)                     \
            aF[0][m] = RD_A(nb, 0, m);                                    \
        BN[0][0] = RD_B(nb, 0, 0);                                        \
        BN[0][1] = RD_B(nb, 0, 1);                                        \
        _Pragma("unroll") for (int m = 0; m < 4; ++m)                     \
        _Pragma("unroll") for (int nn = 0; nn < 2; ++nn)                  \
            acc[m][6+nn] = mfma64(aF[1][m], BC[1][nn], acc[m][6+nn]);     \
        _Pragma("unroll") for (int m = 0; m < 4; ++m)                     \
            aF[1][m] = RD_A(nb, 1, m);                                    \
        BN[1][0] = RD_B(nb, 1, 0);                                        \
        BN[1][1] = RD_B(nb, 1, 1);                                        \
        __builtin_amdgcn_s_setprio(0);                                    \
    } while (0)

// grp3 with no weaves (final tile): still sweep-ordered.
#define MMA_END(BC)                                                       \
    do {                                                                  \
        __builtin_amdgcn_s_setprio(1);                                    \
        _Pragma("unroll") for (int m = 0; m < 4; ++m)                     \
        _Pragma("unroll") for (int nn = 0; nn < 2; ++nn)                  \
            acc[m][6+nn] = mfma64(aF[0][m], BC[0][nn], acc[m][6+nn]);     \
        _Pragma("unroll") for (int m = 0; m < 4; ++m)                     \
        _Pragma("unroll") for (int nn = 0; nn < 2; ++nn)                  \
            acc[m][6+nn] = mfma64(aF[1][m], BC[1][nn], acc[m][6+nn]);     \
        __builtin_amdgcn_s_setprio(0);                                    \
    } while (0)

// One full tile: 64 MFMA, 2 barriers, stages {B(t+1), A(t+2)}.
#define TILE(p, koA, koB)                                                 \
    do {                                                                  \
        STAGE_B((p)^1, 0, koB); STAGE_B((p)^1, 1, koB); STAGE_A(p, 0, koA); \
        MMA_BW(0, bFa, bFb, p, 1);                                        \
        STAGE_A(p, 1, koA);                                               \
        MMA_BW(1, bFb, bFa, p, 2);                                        \
        WAITV(2); BARRIER();                                              \
        MMA_BW(2, bFa, bFb, p, 3);                                        \
        MMA_P4(bFb, bFa, (p)^1);                                          \
        WAITV(2); BARRIER();                                              \
    } while (0)

    // ---- prologue ----
    STAGE_A(0, 0, 0); STAGE_A(0, 1, 0); STAGE_B(0, 0, 0); STAGE_B(0, 1, 0);
    WAITV(0);
    BARRIER();
#pragma unroll
    for (int m = 0; m < 4; ++m) { aF[0][m] = RD_A(0, 0, m); aF[1][m] = RD_A(0, 1, m); }
#pragma unroll
    for (int nn = 0; nn < 2; ++nn) { bFa[0][nn] = RD_B(0, 0, nn); bFa[1][nn] = RD_B(0, 1, nn); }
    LGKM0();
    BARRIER();
    STAGE_A(1, 0, BK); STAGE_A(1, 1, BK);

#pragma unroll 1
    for (int i = 0; i < 15; ++i) {         // tiles 0..29
        const int t2 = 2 * i;
        TILE(0, (t2 + 2) * BK, (t2 + 1) * BK);
        TILE(1, (t2 + 3) * BK, (t2 + 2) * BK);
    }

    // ---- tile 30 (buf0): stage only B(31); drain fully at W2 ----
    STAGE_B(1, 0, 31 * BK); STAGE_B(1, 1, 31 * BK);
    MMA_BW(0, bFa, bFb, 0, 1);
    MMA_BW(1, bFb, bFa, 0, 2);
    WAITV(2); BARRIER();
    MMA_BW(2, bFa, bFb, 0, 3);
    MMA_P4(bFb, bFa, 1);
    WAITV(0); BARRIER();
    // ---- tile 31 (buf1): no stages, no barriers needed ----
    MMA_BW(0, bFa, bFb, 1, 1);
    MMA_BW(1, bFb, bFa, 1, 2);
    MMA_BW(2, bFa, bFb, 1, 3);
    MMA_END(bFb);

    // ---- C write: col = lane&15, row = (lane>>4)*4 + reg ----
#pragma unroll
    for (int m = 0; m < 4; ++m) {
        const int rbase = m0 + wm * 64 + m * 16 + q * 4;
        const float4 s4 = *(const float4*)&sx[rbase];
#pragma unroll
        for (int n = 0; n < 8; ++n) {
            const int col = n0 + wn * 128 + n * 16 + r4;
            const float swc = sw[col];
            float* cp = C + (size_t)rbase * N_DIM + col;
            cp[0 * N_DIM] = (float)acc[m][n][0] * s4.x * swc;
            cp[1 * N_DIM] = (float)acc[m][n][1] * s4.y * swc;
            cp[2 * N_DIM] = (float)acc[m][n][2] * s4.z * swc;
            cp[3 * N_DIM] = (float)acc[m][n][3] * s4.w * swc;
        }
    }
#undef STAGE_A
#undef STAGE_B
#undef RD_A
#undef RD_B
#undef MMA_BW
#undef MMA_P4
#undef MMA_END
#undef TILE
}

// ---------------------------------------------------------------------------
// Launch: ws usage = 16.7 MB xq + 16.7 MB wq + 32 KB scales.
// ---------------------------------------------------------------------------
extern "C" void kernel_launch(void* const* d_in, const int* in_sizes, int n_in,
                              void* d_out, int out_size, void* d_ws, size_t ws_size,
                              hipStream_t stream) {
    const float* x      = (const float*)d_in[0];
    const int*   packed = (const int*)d_in[1];
    const float* d      = (const float*)d_in[2];
    const float* dmin   = (const float*)d_in[3];
    const int*   scales = (const int*)d_in[4];
    const int*   mins   = (const int*)d_in[5];
    float* out = (float*)d_out;

    int8_t* xq = (int8_t*)d_ws;                               // 16.7 MB
    int8_t* wq = xq + (size_t)M_DIM * K_DIM;                  // 16.7 MB
    float*  sx = (float*)(wq + (size_t)N_DIM * K_DIM);        // 16 KB
    float*  sw = sx + M_DIM;                                  // 16 KB

    quant_xw<<<2048, 256, 0, stream>>>(x, packed, d, dmin, scales, mins,
                                       xq, sx, wq, sw);
    gemm_i8<<<256, 512, 0, stream>>>(xq, wq, sx, sw, out);
}

// Round 9
// 215.375 us; speedup vs baseline: 1.0982x; 1.0218x over previous
//
#include <hip/hip_runtime.h>
#include <stdint.h>

// Problem constants (fixed shapes from reference)
#define M_DIM 4096   // 2 * 2048 rows of x
#define K_DIM 4096   // in_features
#define N_DIM 4096   // out_features

typedef float f32x4 __attribute__((ext_vector_type(4)));
typedef int   i32x4 __attribute__((ext_vector_type(4)));

// ---------------------------------------------------------------------------
// Quant (R8, unchanged): one WAVE per row, no LDS/syncthreads, coalesced.
// ---------------------------------------------------------------------------
__global__ __launch_bounds__(256) void quant_xw(const float* __restrict__ x,
                                                const int* __restrict__ packed,
                                                const float* __restrict__ d,
                                                const float* __restrict__ dmin,
                                                const int* __restrict__ scales,
                                                const int* __restrict__ mins,
                                                int8_t* __restrict__ xq,
                                                float* __restrict__ sx,
                                                int8_t* __restrict__ wq,
                                                float* __restrict__ sw) {
    const int wave = threadIdx.x >> 6;
    const int lane = threadIdx.x & 63;
    if (blockIdx.x < 1024) {
        const int row = blockIdx.x * 4 + wave;
        const float4* xr = (const float4*)(x + (size_t)row * K_DIM);
        float4 v[16];
#pragma unroll
        for (int c = 0; c < 16; ++c) v[c] = xr[c * 64 + lane];
        float am = 0.f;
#pragma unroll
        for (int c = 0; c < 16; ++c) {
            am = fmaxf(am, fabsf(v[c].x)); am = fmaxf(am, fabsf(v[c].y));
            am = fmaxf(am, fabsf(v[c].z)); am = fmaxf(am, fabsf(v[c].w));
        }
#pragma unroll
        for (int off = 32; off; off >>= 1) am = fmaxf(am, __shfl_xor(am, off, 64));
        am = fmaxf(am, 1e-20f);
        const float inv = 127.0f / am;
        int* oq = (int*)(xq + (size_t)row * K_DIM);
#pragma unroll
        for (int c = 0; c < 16; ++c) {
            int q0 = __float2int_rn(v[c].x * inv);
            int q1 = __float2int_rn(v[c].y * inv);
            int q2 = __float2int_rn(v[c].z * inv);
            int q3 = __float2int_rn(v[c].w * inv);
            oq[c * 64 + lane] = (q0 & 255) | ((q1 & 255) << 8) |
                                ((q2 & 255) << 16) | ((q3 & 255) << 24);
        }
        if (lane == 0) sx[row] = am / 127.0f;
    } else {
        const int n = (blockIdx.x - 1024) * 4 + wave;
        const int sb = n * 128;
        const float s0  = (float)scales[sb + lane];
        const float s1  = (float)scales[sb + 64 + lane];
        const float mn0 = (float)mins[sb + lane];
        const float mn1 = (float)mins[sb + 64 + lane];
        const int di = n * 16;
        const float dd0 = d[di + (lane >> 3)];
        const float dd1 = d[di + 8 + (lane >> 3)];
        const float dm0 = dmin[di + (lane >> 3)];
        const float dm1 = dmin[di + 8 + (lane >> 3)];
        const float a0 = dd0 * s0 * (1.0f / 945.0f);
        const float b0 = dd0 * mn0 * (1.0f / 63.0f) + dm0;
        const float a1 = dd1 * s1 * (1.0f / 945.0f);
        const float b1 = dd1 * mn1 * (1.0f / 63.0f) + dm1;
        float m = fmaxf(15.0f * a0 + b0, 15.0f * a1 + b1);
#pragma unroll
        for (int off = 32; off; off >>= 1) m = fmaxf(m, __shfl_xor(m, off, 64));
        m = fmaxf(m, 1e-20f);
        const float inv = 127.0f / m;
        const float A0 = a0 * inv, B0 = b0 * inv;
        const float A1 = a1 * inv, B1 = b1 * inv;
        const int4* pr = (const int4*)(packed + (size_t)n * (K_DIM / 2));
        int2* outr = (int2*)(wq + (size_t)n * K_DIM);
#pragma unroll
        for (int c = 0; c < 8; ++c) {
            const int4 pv = pr[c * 64 + lane];
            const int sIdx = (c & 3) * 16 + (lane >> 2);
            const float a = (c < 4) ? __shfl(A0, sIdx, 64) : __shfl(A1, sIdx, 64);
            const float b = (c < 4) ? __shfl(B0, sIdx, 64) : __shfl(B1, sIdx, 64);
            int q0 = __float2int_rn((float)(pv.x & 15) * a + b);
            int q1 = __float2int_rn((float)((pv.x >> 4) & 15) * a + b);
            int q2 = __float2int_rn((float)(pv.y & 15) * a + b);
            int q3 = __float2int_rn((float)((pv.y >> 4) & 15) * a + b);
            int q4 = __float2int_rn((float)(pv.z & 15) * a + b);
            int q5 = __float2int_rn((float)((pv.z >> 4) & 15) * a + b);
            int q6 = __float2int_rn((float)(pv.w & 15) * a + b);
            int q7 = __float2int_rn((float)((pv.w >> 4) & 15) * a + b);
            int2 o;
            o.x = (q0 & 255) | ((q1 & 255) << 8) | ((q2 & 255) << 16) | ((q3 & 255) << 24);
            o.y = (q4 & 255) | ((q5 & 255) << 8) | ((q6 & 255) << 16) | ((q7 & 255) << 24);
            outr[c * 64 + lane] = o;
        }
        if (lane == 0) sw[n] = m / 127.0f;
    }
}

// ---------------------------------------------------------------------------
// GEMM R9 = R5/R8 skeleton + two changes attacking the MEASURED serialization
// (window 2662 cy ~= MFMA 1306 + LDS-port 1408 SUMMED, should be overlapped):
//  (1) sched_group_barrier chains per barrier region force the emitted
//      interleave {4 MFMA, 1-2 ds_read} so the LDS port runs DURING the MFMA
//      stream instead of as a post-barrier read storm (T19 mechanism; the
//      compiler re-clusters source-level weaves otherwise).
//  (2) s_setprio removed (m190: hurts 2-barrier GEMM; prio-1 MFMA wave
//      delays the co-resident wave's reads -> reinforces the storm).
// Everything else (staging, swizzle, WAITV(2) counts, C-write) identical.
// ---------------------------------------------------------------------------
#define BK 128   // bytes of K per K-tile (2 MFMA k-steps of 64)

__device__ __forceinline__ void async_copy16(void* lds, const void* g) {
    __builtin_amdgcn_global_load_lds(
        (const __attribute__((address_space(1))) void*)g,
        (__attribute__((address_space(3))) void*)lds, 16, 0, 0);
}

#define BARRIER() asm volatile("s_barrier" ::: "memory")
#define WAITV(n)  asm volatile("s_waitcnt vmcnt(" #n ")" ::: "memory")
#define LGKM0()   asm volatile("s_waitcnt lgkmcnt(0)" ::: "memory")
#define mfma64(a, b, c) __builtin_amdgcn_mfma_i32_16x16x64_i8(a, b, c, 0, 0, 0)
#define SGB(mask, n) __builtin_amdgcn_sched_group_barrier((mask), (n), 0)

// Region with 32 MFMA + 8 ds_read: 8 x {MFMA x4, DS_READ x1}
#define SGB_CHAIN_8R()                                                    \
    do { _Pragma("unroll") for (int s_ = 0; s_ < 8; ++s_) {               \
        SGB(0x8, 4); SGB(0x100, 1); } } while (0)
// Region with 32 MFMA + 16 ds_read: 8 x {MFMA x4, DS_READ x2}
#define SGB_CHAIN_16R()                                                   \
    do { _Pragma("unroll") for (int s_ = 0; s_ < 8; ++s_) {               \
        SGB(0x8, 4); SGB(0x100, 2); } } while (0)

__global__ __launch_bounds__(512, 2) void gemm_i8(const int8_t* __restrict__ A,
                                                  const int8_t* __restrict__ B,
                                                  const float* __restrict__ sx,
                                                  const float* __restrict__ sw,
                                                  float* __restrict__ C) {
    __shared__ int8_t sA[2][2][128 * 128];
    __shared__ int8_t sB[2][2][128 * 128];

    const int tid  = threadIdx.x;
    const int wave = tid >> 6;
    const int lane = tid & 63;
    const int wm = wave >> 1;       // 0..3  (M split)
    const int wn = wave & 1;        // 0..1  (N split = B half)
    const int r4 = lane & 15;
    const int q  = lane >> 4;
    const int ah = wm >> 1;         // wave's A half region

    // XCD-aware bijective swizzle
    const int bid = blockIdx.x;
    const int lid = (bid & 7) * 32 + (bid >> 3);
    const int m0 = (lid & 15) * 256;
    const int n0 = (lid >> 4) * 256;

    i32x4 acc[4][8] = {};           // [m][n] -> 128 acc regs
    i32x4 aF[2][4];                 // [ks][m]  A(t), held all tile
    i32x4 bFa[2][2], bFb[2][2];     // [ks][nn] ping-pong B groups

    // ---- staging map ----
    const int rowS = tid >> 3;
    const int cS   = (tid & 7) ^ (rowS & 7);
    const size_t rs64 = (size_t)64 * K_DIM;
    const int8_t* gAh[2];
    const int8_t* gBh[2];
    gAh[0] = A + (size_t)(m0 + rowS) * K_DIM + cS * 16;
    gAh[1] = gAh[0] + (size_t)128 * K_DIM;
    gBh[0] = B + (size_t)(n0 + rowS) * K_DIM + cS * 16;
    gBh[1] = gBh[0] + (size_t)128 * K_DIM;
    const int ldsW = wave * 1024;

#define STAGE_A(buf, half, koff)                                          \
    do {                                                                  \
        async_copy16(&sA[buf][half][ldsW],        gAh[half] + (koff));    \
        async_copy16(&sA[buf][half][ldsW + 8192], gAh[half] + rs64 + (koff)); \
    } while (0)
#define STAGE_B(buf, half, koff)                                          \
    do {                                                                  \
        async_copy16(&sB[buf][half][ldsW],        gBh[half] + (koff));    \
        async_copy16(&sB[buf][half][ldsW + 8192], gBh[half] + rs64 + (koff)); \
    } while (0)

    // ---- fragment LDS base offsets ----
    int aOffB[2], bOffB[2];
#pragma unroll
    for (int ks = 0; ks < 2; ++ks) {
        const int sl = (((ks * 4 + q) ^ (r4 & 7)) * 16);
        aOffB[ks] = ((wm & 1) * 64 + r4) * 128 + sl;
        bOffB[ks] = r4 * 128 + sl;
    }

#define RD_A(buf, ks, m) (*(const i32x4*)&sA[buf][ah][aOffB[ks] + (m) * 2048])
#define RD_B(buf, ks, n) (*(const i32x4*)&sB[buf][wn][bOffB[ks] + (n) * 2048])

// 16 MFMA for B-group g: k0 sweep, weave, k1 sweep, weave. (no setprio)
#define MMA_BW(g, BC, BN, rb, ng)                                         \
    do {                                                                  \
        _Pragma("unroll") for (int m = 0; m < 4; ++m)                     \
        _Pragma("unroll") for (int nn = 0; nn < 2; ++nn)                  \
            acc[m][2*(g)+nn] = mfma64(aF[0][m], BC[0][nn], acc[m][2*(g)+nn]); \
        BN[0][0] = RD_B(rb, 0, 2*(ng));                                  \
        BN[0][1] = RD_B(rb, 0, 2*(ng) + 1);                              \
        _Pragma("unroll") for (int m = 0; m < 4; ++m)                     \
        _Pragma("unroll") for (int nn = 0; nn < 2; ++nn)                  \
            acc[m][2*(g)+nn] = mfma64(aF[1][m], BC[1][nn], acc[m][2*(g)+nn]); \
        BN[1][0] = RD_B(rb, 1, 2*(ng));                                  \
        BN[1][1] = RD_B(rb, 1, 2*(ng) + 1);                              \
    } while (0)

// grp3: k0 sweep; weave aF[0]+grp0-B k0; k1 sweep; weave rest.
#define MMA_P4(BC, BN, nb)                                                \
    do {                                                                  \
        _Pragma("unroll") for (int m = 0; m < 4; ++m)                     \
        _Pragma("unroll") for (int nn = 0; nn < 2; ++nn)                  \
            acc[m][6+nn] = mfma64(aF[0][m], BC[0][nn], acc[m][6+nn]);     \
        _Pragma("unroll") for (int m = 0; m < 4; ++m)                     \
            aF[0][m] = RD_A(nb, 0, m);                                    \
        BN[0][0] = RD_B(nb, 0, 0);                                        \
        BN[0][1] = RD_B(nb, 0, 1);                                        \
        _Pragma("unroll") for (int m = 0; m < 4; ++m)                     \
        _Pragma("unroll") for (int nn = 0; nn < 2; ++nn)                  \
            acc[m][6+nn] = mfma64(aF[1][m], BC[1][nn], acc[m][6+nn]);     \
        _Pragma("unroll") for (int m = 0; m < 4; ++m)                     \
            aF[1][m] = RD_A(nb, 1, m);                                    \
        BN[1][0] = RD_B(nb, 1, 0);                                        \
        BN[1][1] = RD_B(nb, 1, 1);                                        \
    } while (0)

// grp3 with no weaves (final tile).
#define MMA_END(BC)                                                       \
    do {                                                                  \
        _Pragma("unroll") for (int m = 0; m < 4; ++m)                     \
        _Pragma("unroll") for (int nn = 0; nn < 2; ++nn)                  \
            acc[m][6+nn] = mfma64(aF[0][m], BC[0][nn], acc[m][6+nn]);     \
        _Pragma("unroll") for (int m = 0; m < 4; ++m)                     \
        _Pragma("unroll") for (int nn = 0; nn < 2; ++nn)                  \
            acc[m][6+nn] = mfma64(aF[1][m], BC[1][nn], acc[m][6+nn]);     \
    } while (0)

// One full tile: 64 MFMA, 2 barriers, stages {B(t+1), A(t+2)}.
// SGB chains pin the emitted interleave in each barrier region.
#define TILE(p, koA, koB)                                                 \
    do {                                                                  \
        STAGE_B((p)^1, 0, koB); STAGE_B((p)^1, 1, koB); STAGE_A(p, 0, koA); \
        MMA_BW(0, bFa, bFb, p, 1);                                        \
        STAGE_A(p, 1, koA);                                               \
        MMA_BW(1, bFb, bFa, p, 2);                                        \
        SGB_CHAIN_8R();                                                   \
        WAITV(2); BARRIER();                                              \
        MMA_BW(2, bFa, bFb, p, 3);                                        \
        MMA_P4(bFb, bFa, (p)^1);                                          \
        SGB_CHAIN_16R();                                                  \
        WAITV(2); BARRIER();                                              \
    } while (0)

    // ---- prologue ----
    STAGE_A(0, 0, 0); STAGE_A(0, 1, 0); STAGE_B(0, 0, 0); STAGE_B(0, 1, 0);
    WAITV(0);
    BARRIER();
#pragma unroll
    for (int m = 0; m < 4; ++m) { aF[0][m] = RD_A(0, 0, m); aF[1][m] = RD_A(0, 1, m); }
#pragma unroll
    for (int nn = 0; nn < 2; ++nn) { bFa[0][nn] = RD_B(0, 0, nn); bFa[1][nn] = RD_B(0, 1, nn); }
    LGKM0();
    BARRIER();
    STAGE_A(1, 0, BK); STAGE_A(1, 1, BK);

#pragma unroll 1
    for (int i = 0; i < 15; ++i) {         // tiles 0..29
        const int t2 = 2 * i;
        TILE(0, (t2 + 2) * BK, (t2 + 1) * BK);
        TILE(1, (t2 + 3) * BK, (t2 + 2) * BK);
    }

    // ---- tile 30 (buf0): stage only B(31); drain fully at W2 ----
    STAGE_B(1, 0, 31 * BK); STAGE_B(1, 1, 31 * BK);
    MMA_BW(0, bFa, bFb, 0, 1);
    MMA_BW(1, bFb, bFa, 0, 2);
    SGB_CHAIN_8R();
    WAITV(2); BARRIER();
    MMA_BW(2, bFa, bFb, 0, 3);
    MMA_P4(bFb, bFa, 1);
    SGB_CHAIN_16R();
    WAITV(0); BARRIER();
    // ---- tile 31 (buf1): no stages, no barriers needed ----
    MMA_BW(0, bFa, bFb, 1, 1);
    MMA_BW(1, bFb, bFa, 1, 2);
    MMA_BW(2, bFa, bFb, 1, 3);
    MMA_END(bFb);

    // ---- C write: col = lane&15, row = (lane>>4)*4 + reg ----
#pragma unroll
    for (int m = 0; m < 4; ++m) {
        const int rbase = m0 + wm * 64 + m * 16 + q * 4;
        const float4 s4 = *(const float4*)&sx[rbase];
#pragma unroll
        for (int n = 0; n < 8; ++n) {
            const int col = n0 + wn * 128 + n * 16 + r4;
            const float swc = sw[col];
            float* cp = C + (size_t)rbase * N_DIM + col;
            cp[0 * N_DIM] = (float)acc[m][n][0] * s4.x * swc;
            cp[1 * N_DIM] = (float)acc[m][n][1] * s4.y * swc;
            cp[2 * N_DIM] = (float)acc[m][n][2] * s4.z * swc;
            cp[3 * N_DIM] = (float)acc[m][n][3] * s4.w * swc;
        }
    }
#undef STAGE_A
#undef STAGE_B
#undef RD_A
#undef RD_B
#undef MMA_BW
#undef MMA_P4
#undef MMA_END
#undef TILE
}

// ---------------------------------------------------------------------------
// Launch: ws usage = 16.7 MB xq + 16.7 MB wq + 32 KB scales.
// ---------------------------------------------------------------------------
extern "C" void kernel_launch(void* const* d_in, const int* in_sizes, int n_in,
                              void* d_out, int out_size, void* d_ws, size_t ws_size,
                              hipStream_t stream) {
    const float* x      = (const float*)d_in[0];
    const int*   packed = (const int*)d_in[1];
    const float* d      = (const float*)d_in[2];
    const float* dmin   = (const float*)d_in[3];
    const int*   scales = (const int*)d_in[4];
    const int*   mins   = (const int*)d_in[5];
    float* out = (float*)d_out;

    int8_t* xq = (int8_t*)d_ws;                               // 16.7 MB
    int8_t* wq = xq + (size_t)M_DIM * K_DIM;                  // 16.7 MB
    float*  sx = (float*)(wq + (size_t)N_DIM * K_DIM);        // 16 KB
    float*  sw = sx + M_DIM;                                  // 16 KB

    quant_xw<<<2048, 256, 0, stream>>>(x, packed, d, dmin, scales, mins,
                                       xq, sx, wq, sw);
    gemm_i8<<<256, 512, 0, stream>>>(xq, wq, sx, sw, out);
}